// Round 1
// baseline (180.732 us; speedup 1.0000x reference)
//
#include <hip/hip_runtime.h>

// Additive attention, fully fused:
//   scores[b,q,k] = sum_h w_v[h] * tanh(qp[b,q,h] + kp[b,k,h])
// Key identity: tanh(x) = 1 - 2/(1 + e^{2x}) and e^{2(qp+kp)} = Eq*Ek with
// Eq = e^{2*qp}, Ek = e^{2*kp} precomputed. The constant sum_h w_h cancels in
// softmax, so score' = sum_h (-2 w_h) / (1 + Eq*Ek): 3 VALU ops/element.
// Masked k (>= valid_len) are skipped entirely (their softmax weight is 0).
//
// Kernel 1: fp32 GEMM projections + exp2, storing TRANSPOSED [b][h][row] so
//           kernel 2 reads Ek coalesced along k and Eq/w_v via scalar loads.
// Kernel 2: per (b, 4 q's): scores -> LDS, masked softmax, P@V with values
//           read once per block.

#define Bb 8
#define Qn 256
#define Kk 1024
#define Dd 256
#define Hh 128
#define DVv 128

__device__ __forceinline__ float fexp2(float x) { return __builtin_amdgcn_exp2f(x); }
__device__ __forceinline__ float frcp(float x)  { return __builtin_amdgcn_rcpf(x); }

// ---------------------------------------------------------------------------
// Kernel 1: out_T[b][h][r] = exp2( (sum_d X[bR+r][d]*W[h][d]) * 2*log2(e) )
// blocks 0..63 -> queries (RB=256), blocks 64..319 -> keys (RB=1024).
// Block = 64 rows x 64 h-cols; wave w handles 16 h; lane = row.
// X rows staged in LDS (stride 65 -> 2-way bank alias, free); W via s_loads.
// ---------------------------------------------------------------------------
__global__ __launch_bounds__(256, 4)
void proj_exp_kernel(const float* __restrict__ queries,
                     const float* __restrict__ keys,
                     const float* __restrict__ Wq,
                     const float* __restrict__ Wk,
                     float* __restrict__ EqT,
                     float* __restrict__ EkT)
{
    __shared__ float As[64 * 65];
    const int blk = blockIdx.x;
    const float* X; const float* W; float* outT; int RB; int tile;
    if (blk < 64) { X = queries; W = Wq; outT = EqT; RB = Qn; tile = blk; }
    else          { X = keys;    W = Wk; outT = EkT; RB = Kk; tile = blk - 64; }
    const int rowTile = tile >> 1;
    const int hHalf   = tile & 1;
    const int i0      = rowTile * 64;
    const int tid  = threadIdx.x;
    const int lane = tid & 63;
    const int wave = __builtin_amdgcn_readfirstlane(tid >> 6);
    const int h0   = hHalf * 64 + wave * 16;

    float acc[16];
#pragma unroll
    for (int j = 0; j < 16; ++j) acc[j] = 0.f;

    for (int d0 = 0; d0 < Dd; d0 += 64) {
        __syncthreads();
#pragma unroll
        for (int s = 0; s < 4; ++s) {
            const int idx = tid + 256 * s;   // 1024 float4 slots = 64 rows x 16
            const int r = idx >> 4;
            const int c = (idx & 15) << 2;
            const float4 v = *(const float4*)(X + (size_t)(i0 + r) * Dd + d0 + c);
            float* dst = &As[r * 65 + c];
            dst[0] = v.x; dst[1] = v.y; dst[2] = v.z; dst[3] = v.w;
        }
        __syncthreads();
        const float* wp0 = W + (size_t)h0 * Dd + d0;
#pragma unroll 4
        for (int d = 0; d < 64; ++d) {
            const float a = As[lane * 65 + d];
#pragma unroll
            for (int j = 0; j < 16; ++j)
                acc[j] = fmaf(a, wp0[(size_t)j * Dd + d], acc[j]);   // W -> SGPR
        }
    }
    const int b    = i0 / RB;
    const int rloc = (i0 % RB) + lane;
    float* dst = outT + (size_t)b * Hh * RB + rloc;
#pragma unroll
    for (int j = 0; j < 16; ++j)
        dst[(size_t)(h0 + j) * RB] = fexp2(acc[j] * 2.885390082f);   // e^{2x}
}

// ---------------------------------------------------------------------------
// Kernel 2: one block per (b, q0..q0+3). 256 threads.
// Phase 1: scores (3 VALU/elem), Ek coalesced global, Eq/w_v scalar loads.
// Phase 2: per-q masked softmax (wave = q).
// Phase 3: P@V, values read once per block, 8 k-slices + LDS combine.
// ---------------------------------------------------------------------------
__global__ __launch_bounds__(256, 4)
void attn_kernel(const float* __restrict__ EqT,
                 const float* __restrict__ EkT,
                 const float* __restrict__ wv,
                 const float* __restrict__ values,
                 const int* __restrict__ valid_lens,
                 float* __restrict__ out)
{
    __shared__ float  s_sc[4][Kk];       // 16 KB: scores, then softmax weights
    __shared__ float4 s_part[3][4][32];  // 6 KB: phase-3 partials (waves 1..3)
    __shared__ float  s_inv[4];

    const int blk  = blockIdx.x;         // 512 blocks
    const int b    = blk >> 6;
    const int q0   = (blk & 63) << 2;
    const int tid  = threadIdx.x;
    const int lane = tid & 63;
    const int wave = __builtin_amdgcn_readfirstlane(tid >> 6);
    const int len  = valid_lens[b];      // uniform

    const float* eqB = EqT + (size_t)b * Hh * Qn + q0;   // [h][q], stride Qn
    const float* ekB = EkT + (size_t)b * Hh * Kk;        // [h][k], stride Kk

    // ---- phase 1: scores for k < len (wave-granular skip of masked range)
    for (int j = 0; j < 4; ++j) {
        const int kw = wave * 64 + 256 * j;
        if (kw >= len) break;            // uniform per wave; monotonic in j
        const int k = kw + lane;
        const float* ekp = ekB + k;
        float a0 = 0.f, a1 = 0.f, a2 = 0.f, a3 = 0.f;
        for (int h = 0; h < Hh; h += 4) {
#pragma unroll
            for (int t = 0; t < 4; ++t) {
                const float ek = ekp[(size_t)(h + t) * Kk];   // coalesced b32
                const float w2 = -2.0f * wv[h + t];           // scalar
                const float* eqh = eqB + (size_t)(h + t) * Qn;
                const float e0 = eqh[0], e1 = eqh[1], e2 = eqh[2], e3 = eqh[3];
                a0 = fmaf(w2, frcp(fmaf(e0, ek, 1.0f)), a0);
                a1 = fmaf(w2, frcp(fmaf(e1, ek, 1.0f)), a1);
                a2 = fmaf(w2, frcp(fmaf(e2, ek, 1.0f)), a2);
                a3 = fmaf(w2, frcp(fmaf(e3, ek, 1.0f)), a3);
            }
        }
        s_sc[0][k] = a0; s_sc[1][k] = a1; s_sc[2][k] = a2; s_sc[3][k] = a3;
    }
    __syncthreads();

    // ---- phase 2: masked softmax, wave w owns q = w
    {
        const int q = wave;
        float m = -3.0e38f;
        for (int i = lane; i < len; i += 64) m = fmaxf(m, s_sc[q][i]);
#pragma unroll
        for (int off = 32; off > 0; off >>= 1) m = fmaxf(m, __shfl_xor(m, off));
        float sum = 0.f;
        for (int i = lane; i < len; i += 64) {
            const float p = fexp2((s_sc[q][i] - m) * 1.44269504f);
            s_sc[q][i] = p;
            sum += p;
        }
#pragma unroll
        for (int off = 32; off > 0; off >>= 1) sum += __shfl_xor(sum, off);
        if (lane == 0) s_inv[q] = frcp(sum);
    }
    __syncthreads();

    // ---- phase 3: out[b][q0+q][:] = inv[q] * sum_{k<len} w[q][k]*values[b][k][:]
    {
        const int slice = tid >> 5;          // 8 k-slices
        const int l32   = tid & 31;
        const int v4    = l32 << 2;          // 32 lanes x float4 = 128 v
        const float* vp = values + (size_t)b * Kk * DVv + v4;
        float a[4][4];
#pragma unroll
        for (int q = 0; q < 4; ++q) { a[q][0]=0.f; a[q][1]=0.f; a[q][2]=0.f; a[q][3]=0.f; }
        for (int k = slice; k < len; k += 8) {
            const float4 val = *(const float4*)(vp + (size_t)k * DVv);
            const float w0 = s_sc[0][k], w1 = s_sc[1][k], w2 = s_sc[2][k], w3 = s_sc[3][k];
            a[0][0] = fmaf(w0, val.x, a[0][0]);
            a[0][1] = fmaf(w0, val.y, a[0][1]);
            a[0][2] = fmaf(w0, val.z, a[0][2]);
            a[0][3] = fmaf(w0, val.w, a[0][3]);
            a[1][0] = fmaf(w1, val.x, a[1][0]);
            a[1][1] = fmaf(w1, val.y, a[1][1]);
            a[1][2] = fmaf(w1, val.z, a[1][2]);
            a[1][3] = fmaf(w1, val.w, a[1][3]);
            a[2][0] = fmaf(w2, val.x, a[2][0]);
            a[2][1] = fmaf(w2, val.y, a[2][1]);
            a[2][2] = fmaf(w2, val.z, a[2][2]);
            a[2][3] = fmaf(w2, val.w, a[2][3]);
            a[3][0] = fmaf(w3, val.x, a[3][0]);
            a[3][1] = fmaf(w3, val.y, a[3][1]);
            a[3][2] = fmaf(w3, val.z, a[3][2]);
            a[3][3] = fmaf(w3, val.w, a[3][3]);
        }
        // fold the two slices of each wave together
#pragma unroll
        for (int q = 0; q < 4; ++q)
#pragma unroll
            for (int x = 0; x < 4; ++x) a[q][x] += __shfl_xor(a[q][x], 32);
        if (wave > 0 && lane < 32) {
#pragma unroll
            for (int q = 0; q < 4; ++q)
                s_part[wave - 1][q][l32] = make_float4(a[q][0], a[q][1], a[q][2], a[q][3]);
        }
        __syncthreads();
        if (wave == 0 && lane < 32) {
#pragma unroll
            for (int q = 0; q < 4; ++q) {
                const float inv = s_inv[q];
                const float4 p0 = s_part[0][q][l32];
                const float4 p1 = s_part[1][q][l32];
                const float4 p2 = s_part[2][q][l32];
                const float r0 = (a[q][0] + p0.x + p1.x + p2.x) * inv;
                const float r1 = (a[q][1] + p0.y + p1.y + p2.y) * inv;
                const float r2 = (a[q][2] + p0.z + p1.z + p2.z) * inv;
                const float r3 = (a[q][3] + p0.w + p1.w + p2.w) * inv;
                *(float4*)(out + (size_t)(b * Qn + q0 + q) * DVv + v4) =
                    make_float4(r0, r1, r2, r3);
            }
        }
    }
}

extern "C" void kernel_launch(void* const* d_in, const int* in_sizes, int n_in,
                              void* d_out, int out_size, void* d_ws, size_t ws_size,
                              hipStream_t stream) {
    (void)in_sizes; (void)n_in; (void)out_size; (void)ws_size;
    const float* queries    = (const float*)d_in[0];
    const float* keys       = (const float*)d_in[1];
    const float* values     = (const float*)d_in[2];
    const int*   valid_lens = (const int*)  d_in[3];
    const float* Wq         = (const float*)d_in[4];
    const float* Wk         = (const float*)d_in[5];
    const float* wvv        = (const float*)d_in[6];
    float* out = (float*)d_out;

    float* EqT = (float*)d_ws;                          // 8*128*256  = 1 MB
    float* EkT = EqT + (size_t)Bb * Hh * Qn;            // 8*128*1024 = 4 MB

    proj_exp_kernel<<<320, 256, 0, stream>>>(queries, keys, Wq, Wk, EqT, EkT);
    attn_kernel<<<512, 256, 0, stream>>>(EqT, EkT, wvv, values, valid_lens, out);
}

// Round 2
// 165.379 us; speedup vs baseline: 1.0928x; 1.0928x over previous
//
#include <hip/hip_runtime.h>

// Additive attention, factored:
//   scores'[b,q,k] = sum_h (-2 w_h) / (1 + Eq[b,q,h]*Ek[b,k,h]),  Eq=e^{2qp}, Ek=e^{2kp}
// (constant sum_h w_h cancels in softmax). 3 VALU ops per (q,k,h) element.
//
// K0: transpose Wq/Wk -> [D][H] so proj W-loads are lane-coalesced.
// K1: projections + exp, X rows via wave-uniform s_loads, output TRANSPOSED [b][h][r].
// K2: scores -> global ws. 2048 blocks (b x 32 qtile x 8 ktile), masked tiles skipped.
// K3: per (b,4q): masked softmax + P@V.

#define Bb 8
#define Qn 256
#define Kk 1024
#define Dd 256
#define Hh 128
#define DVv 128

__device__ __forceinline__ float fexp2(float x) { return __builtin_amdgcn_exp2f(x); }
__device__ __forceinline__ float frcp(float x)  { return __builtin_amdgcn_rcpf(x); }

// ---------------------------------------------------------------------------
// K0: W [H][D] -> WT [D][H], both matrices. 64 blocks x 256 threads.
// ---------------------------------------------------------------------------
__global__ __launch_bounds__(256)
void transpose_w(const float* __restrict__ Wq, const float* __restrict__ Wk,
                 float* __restrict__ WqT, float* __restrict__ WkT)
{
    __shared__ float t[32][33];
    const int blk = blockIdx.x;                 // mat = blk>>5, tile = blk&31
    const float* src = (blk < 32) ? Wq : Wk;
    float*       dst = (blk < 32) ? WqT : WkT;
    const int tile = blk & 31;                  // 8 d-tiles x 4 h-tiles
    const int d0 = (tile >> 2) * 32, h0 = (tile & 3) * 32;
    const int tx = threadIdx.x & 31, ty = threadIdx.x >> 5;   // 32 x 8
#pragma unroll
    for (int j = 0; j < 4; ++j)
        t[ty + 8 * j][tx] = src[(size_t)(h0 + ty + 8 * j) * Dd + d0 + tx];
    __syncthreads();
#pragma unroll
    for (int j = 0; j < 4; ++j)
        dst[(size_t)(d0 + ty + 8 * j) * Hh + h0 + tx] = t[tx][ty + 8 * j];
}

// ---------------------------------------------------------------------------
// K1: EqT[b][h][r] / EkT[b][h][r] = exp2(2*log2e * X[r]·W[h]).
// 640 blocks x 512 threads; block = 16 rows x 128 h; thread = 4 rows x 1 h.
// X rows wave-uniform -> scalar loads; WT loads lane-coalesced along h.
// ---------------------------------------------------------------------------
__global__ __launch_bounds__(512)
void proj_exp_kernel(const float* __restrict__ queries,
                     const float* __restrict__ keys,
                     const float* __restrict__ WqT,
                     const float* __restrict__ WkT,
                     float* __restrict__ EqT,
                     float* __restrict__ EkT)
{
    const int blk = blockIdx.x;                 // 0..127 queries, 128..639 keys
    const float* X; const float* WT; float* outT; int RB; int i0;
    if (blk < 128) { X = queries; WT = WqT; outT = EqT; RB = Qn; i0 = blk * 16; }
    else           { X = keys;    WT = WkT; outT = EkT; RB = Kk; i0 = (blk - 128) * 16; }
    const int tid = threadIdx.x;
    const int h   = tid & 127;
    const int rq  = __builtin_amdgcn_readfirstlane(tid >> 7);   // 0..3, wave-uniform
    const int rbase = i0 + rq * 4;

    float acc[4] = {0.f, 0.f, 0.f, 0.f};
    for (int d0 = 0; d0 < Dd; d0 += 8) {
        float xr[4][8];
#pragma unroll
        for (int i = 0; i < 4; ++i)
#pragma unroll
            for (int dd = 0; dd < 8; ++dd)
                xr[i][dd] = X[(size_t)(rbase + i) * Dd + d0 + dd];   // s_load_dwordx8
#pragma unroll
        for (int dd = 0; dd < 8; ++dd) {
            const float w = WT[(size_t)(d0 + dd) * Hh + h];          // coalesced
#pragma unroll
            for (int i = 0; i < 4; ++i) acc[i] = fmaf(xr[i][dd], w, acc[i]);
        }
    }
    const int b    = i0 / RB;                   // 16 | RB, never straddles b
    const int rloc = (i0 % RB) + rq * 4;
    float4 o;
    o.x = fexp2(acc[0] * 2.885390082f);         // e^{2x} = 2^{2x*log2e}
    o.y = fexp2(acc[1] * 2.885390082f);
    o.z = fexp2(acc[2] * 2.885390082f);
    o.w = fexp2(acc[3] * 2.885390082f);
    *(float4*)(outT + (size_t)b * Hh * RB + (size_t)h * RB + rloc) = o;
}

// ---------------------------------------------------------------------------
// K2: scores -> S[b][q][k]. 2048 blocks (b<<8 | qt<<3 | kt), 256 threads.
// Thread = 1 k x 4 q; Ek coalesced global (reused 4x), eq/wv scalar loads.
// Masked k-tiles exit immediately; partial garbage beyond len is never read.
// ---------------------------------------------------------------------------
__global__ __launch_bounds__(256)
void score_kernel(const float* __restrict__ EqT,
                  const float* __restrict__ EkT,
                  const float* __restrict__ wv,
                  const int* __restrict__ valid_lens,
                  float* __restrict__ S)
{
    const int blk = blockIdx.x;
    const int b   = blk >> 8;
    const int rem = blk & 255;
    const int qt  = rem >> 3;
    const int kt  = rem & 7;
    const int len = valid_lens[b];
    if (kt * 128 >= len) return;                // uniform early-exit

    const int tid = threadIdx.x;
    const int k   = kt * 128 + (tid & 127);
    const int qh  = __builtin_amdgcn_readfirstlane(tid >> 7);
    const int q0  = qt * 8 + qh * 4;

    const float* eq  = EqT + (size_t)b * Hh * Qn + q0;   // [h][4], scalar
    const float* ekp = EkT + (size_t)b * Hh * Kk + k;    // [h], lane-coalesced

    float a0 = 0.f, a1 = 0.f, a2 = 0.f, a3 = 0.f;
#pragma unroll 4
    for (int h = 0; h < Hh; ++h) {
        const float ek = ekp[(size_t)h * Kk];
        const float w2 = -2.0f * wv[h];
        const float* e = eq + (size_t)h * Qn;
        const float e0 = e[0], e1 = e[1], e2 = e[2], e3 = e[3];
        a0 = fmaf(w2, frcp(fmaf(e0, ek, 1.0f)), a0);
        a1 = fmaf(w2, frcp(fmaf(e1, ek, 1.0f)), a1);
        a2 = fmaf(w2, frcp(fmaf(e2, ek, 1.0f)), a2);
        a3 = fmaf(w2, frcp(fmaf(e3, ek, 1.0f)), a3);
    }
    float* srow = S + (size_t)(b * Qn + q0) * Kk + k;
    srow[0]          = a0;
    srow[Kk]         = a1;
    srow[2 * (size_t)Kk] = a2;
    srow[3 * (size_t)Kk] = a3;
}

// ---------------------------------------------------------------------------
// K3: per (b, 4 q): load scores, masked softmax, P@V. 512 blocks x 256 thr.
// ---------------------------------------------------------------------------
__global__ __launch_bounds__(256, 4)
void softmax_pv_kernel(const float* __restrict__ S,
                       const float* __restrict__ values,
                       const int* __restrict__ valid_lens,
                       float* __restrict__ out)
{
    __shared__ float  s_sc[4][Kk];       // 16 KB
    __shared__ float4 s_part[3][4][32];  // 6 KB
    __shared__ float  s_inv[4];

    const int blk  = blockIdx.x;
    const int b    = blk >> 6;
    const int q0   = (blk & 63) << 2;
    const int tid  = threadIdx.x;
    const int lane = tid & 63;
    const int wave = __builtin_amdgcn_readfirstlane(tid >> 6);
    const int len  = valid_lens[b];

    // ---- load scores (k < len only)
#pragma unroll
    for (int j = 0; j < 4; ++j) {
        const float* sr = S + (size_t)(b * Qn + q0 + j) * Kk;
        for (int k = tid; k < len; k += 256) s_sc[j][k] = sr[k];
    }
    __syncthreads();

    // ---- masked softmax, wave w owns q = w
    {
        const int q = wave;
        float m = -3.0e38f;
        for (int i = lane; i < len; i += 64) m = fmaxf(m, s_sc[q][i]);
#pragma unroll
        for (int off = 32; off > 0; off >>= 1) m = fmaxf(m, __shfl_xor(m, off));
        float sum = 0.f;
        for (int i = lane; i < len; i += 64) {
            const float p = fexp2((s_sc[q][i] - m) * 1.44269504f);
            s_sc[q][i] = p;
            sum += p;
        }
#pragma unroll
        for (int off = 32; off > 0; off >>= 1) sum += __shfl_xor(sum, off);
        if (lane == 0) s_inv[q] = frcp(sum);
    }
    __syncthreads();

    // ---- P@V: values read once per block, 8 k-slices + LDS combine
    {
        const int slice = tid >> 5;
        const int l32   = tid & 31;
        const int v4    = l32 << 2;
        const float* vp = values + (size_t)b * Kk * DVv + v4;
        float a[4][4];
#pragma unroll
        for (int q = 0; q < 4; ++q) { a[q][0]=0.f; a[q][1]=0.f; a[q][2]=0.f; a[q][3]=0.f; }
        for (int k = slice; k < len; k += 8) {
            const float4 val = *(const float4*)(vp + (size_t)k * DVv);
            const float w0 = s_sc[0][k], w1 = s_sc[1][k], w2 = s_sc[2][k], w3 = s_sc[3][k];
            a[0][0] = fmaf(w0, val.x, a[0][0]);
            a[0][1] = fmaf(w0, val.y, a[0][1]);
            a[0][2] = fmaf(w0, val.z, a[0][2]);
            a[0][3] = fmaf(w0, val.w, a[0][3]);
            a[1][0] = fmaf(w1, val.x, a[1][0]);
            a[1][1] = fmaf(w1, val.y, a[1][1]);
            a[1][2] = fmaf(w1, val.z, a[1][2]);
            a[1][3] = fmaf(w1, val.w, a[1][3]);
            a[2][0] = fmaf(w2, val.x, a[2][0]);
            a[2][1] = fmaf(w2, val.y, a[2][1]);
            a[2][2] = fmaf(w2, val.z, a[2][2]);
            a[2][3] = fmaf(w2, val.w, a[2][3]);
            a[3][0] = fmaf(w3, val.x, a[3][0]);
            a[3][1] = fmaf(w3, val.y, a[3][1]);
            a[3][2] = fmaf(w3, val.z, a[3][2]);
            a[3][3] = fmaf(w3, val.w, a[3][3]);
        }
#pragma unroll
        for (int q = 0; q < 4; ++q)
#pragma unroll
            for (int x = 0; x < 4; ++x) a[q][x] += __shfl_xor(a[q][x], 32);
        if (wave > 0 && lane < 32) {
#pragma unroll
            for (int q = 0; q < 4; ++q)
                s_part[wave - 1][q][l32] = make_float4(a[q][0], a[q][1], a[q][2], a[q][3]);
        }
        __syncthreads();
        if (wave == 0 && lane < 32) {
#pragma unroll
            for (int q = 0; q < 4; ++q) {
                const float inv = s_inv[q];
                const float4 p0 = s_part[0][q][l32];
                const float4 p1 = s_part[1][q][l32];
                const float4 p2 = s_part[2][q][l32];
                *(float4*)(out + (size_t)(b * Qn + q0 + q) * DVv + v4) =
                    make_float4((a[q][0] + p0.x + p1.x + p2.x) * inv,
                                (a[q][1] + p0.y + p1.y + p2.y) * inv,
                                (a[q][2] + p0.z + p1.z + p2.z) * inv,
                                (a[q][3] + p0.w + p1.w + p2.w) * inv);
            }
        }
    }
}

extern "C" void kernel_launch(void* const* d_in, const int* in_sizes, int n_in,
                              void* d_out, int out_size, void* d_ws, size_t ws_size,
                              hipStream_t stream) {
    (void)in_sizes; (void)n_in; (void)out_size; (void)ws_size;
    const float* queries    = (const float*)d_in[0];
    const float* keys       = (const float*)d_in[1];
    const float* values     = (const float*)d_in[2];
    const int*   valid_lens = (const int*)  d_in[3];
    const float* Wq         = (const float*)d_in[4];
    const float* Wk         = (const float*)d_in[5];
    const float* wvv        = (const float*)d_in[6];
    float* out = (float*)d_out;

    float* WqT = (float*)d_ws;                                   // 256*128
    float* WkT = WqT + (size_t)Dd * Hh;                          // 256*128
    float* EqT = WkT + (size_t)Dd * Hh;                          // 8*128*256
    float* EkT = EqT + (size_t)Bb * Hh * Qn;                     // 8*128*1024
    float* S   = EkT + (size_t)Bb * Hh * Kk;                     // 8*256*1024

    transpose_w    <<<  64, 256, 0, stream>>>(Wq, Wk, WqT, WkT);
    proj_exp_kernel<<< 640, 512, 0, stream>>>(queries, keys, WqT, WkT, EqT, EkT);
    score_kernel   <<<2048, 256, 0, stream>>>(EqT, EkT, wvv, valid_lens, S);
    softmax_pv_kernel<<<512, 256, 0, stream>>>(S, values, valid_lens, out);
}

// Round 3
// 145.043 us; speedup vs baseline: 1.2461x; 1.1402x over previous
//
#include <hip/hip_runtime.h>

// Additive attention, factored:
//   scores'[b,q,k] = sum_h (-2 w_h) / (1 + Eq[b,q,h]*Ek[b,k,h]),  Eq=e^{2qp}, Ek=e^{2kp}
// (constant sum_h w_h cancels in softmax). 3 VALU ops per (q,k,h) element.
//
// K0: repack Wq/Wk -> W4T[d/4][h] (float4 of W[h][4d..4d+3]) for vectorized proj loads.
// K1: projections + exp. X tile staged in LDS (broadcast reads), W4T float4 loads.
// K2: scores -> S. eq-tile + w2 staged in LDS; 8 q per thread; b fastest-varying.
// K3: masked softmax + P@V; 512 thr, 16 k-slices; b fastest-varying for balance.

#define Bb 8
#define Qn 256
#define Kk 1024
#define Dd 256
#define Hh 128
#define DVv 128

__device__ __forceinline__ float fexp2(float x) { return __builtin_amdgcn_exp2f(x); }
__device__ __forceinline__ float frcp(float x)  { return __builtin_amdgcn_rcpf(x); }

// ---------------------------------------------------------------------------
// K0: W [H][D] -> W4T [D/4][H] float4. 64 blocks x 256 threads.
// Writes coalesced (lane = h); reads scattered but total is only 256 KB.
// ---------------------------------------------------------------------------
__global__ __launch_bounds__(256)
void repack_w(const float* __restrict__ Wq, const float* __restrict__ Wk,
              float4* __restrict__ Wq4T, float4* __restrict__ Wk4T)
{
    const int blk = blockIdx.x;
    const float* src = (blk < 32) ? Wq : Wk;
    float4*      dst = (blk < 32) ? Wq4T : Wk4T;
    const int idx = (blk & 31) * 256 + threadIdx.x;   // 8192 float4 per matrix
    const int g = idx >> 7;          // d-group 0..63
    const int h = idx & 127;
    dst[idx] = *(const float4*)(src + (size_t)h * Dd + g * 4);
}

// ---------------------------------------------------------------------------
// K1: EqT[b][h][r] = exp2(2*log2e * X[r]·W[h]). 640 blocks x 512 threads.
// Block = 16 rows x 128 h; thread = 4 rows x 1 h.
// X tile in LDS (16 KB); per-wave LDS reads are same-address broadcasts.
// ---------------------------------------------------------------------------
__global__ __launch_bounds__(512)
void proj_exp_kernel(const float* __restrict__ queries,
                     const float* __restrict__ keys,
                     const float4* __restrict__ Wq4T,
                     const float4* __restrict__ Wk4T,
                     float* __restrict__ EqT,
                     float* __restrict__ EkT)
{
    __shared__ float Xs[16 * 256];               // 16 KB
    const int blk = blockIdx.x;                  // 0..127 queries, 128..639 keys
    const float* X; const float4* W4; float* outT; int RB; int i0;
    if (blk < 128) { X = queries; W4 = Wq4T; outT = EqT; RB = Qn; i0 = blk * 16; }
    else           { X = keys;    W4 = Wk4T; outT = EkT; RB = Kk; i0 = (blk - 128) * 16; }
    const int tid = threadIdx.x;
    const int h   = tid & 127;
    const int r4  = __builtin_amdgcn_readfirstlane(tid >> 7);   // 0..3, wave-uniform

    // stage 16x256 X tile, coalesced float4
    {
        const float4* xsrc = (const float4*)(X + (size_t)i0 * Dd);
#pragma unroll
        for (int s = 0; s < 2; ++s) {
            const int idx = tid + 512 * s;       // 1024 float4
            *(float4*)(Xs + idx * 4) = xsrc[idx];
        }
    }
    __syncthreads();

    float acc[4] = {0.f, 0.f, 0.f, 0.f};
    const float4* wp = W4 + h;                   // stride 128 float4 per group
    const float*  xr = Xs + (r4 * 4) * 256;
#pragma unroll 8
    for (int g = 0; g < 64; ++g) {
        const float4 w = wp[(size_t)g * 128];    // coalesced dwordx4
#pragma unroll
        for (int i = 0; i < 4; ++i) {
            const float4 x = *(const float4*)(xr + i * 256 + g * 4);  // broadcast b128
            acc[i] = fmaf(x.x, w.x, acc[i]);
            acc[i] = fmaf(x.y, w.y, acc[i]);
            acc[i] = fmaf(x.z, w.z, acc[i]);
            acc[i] = fmaf(x.w, w.w, acc[i]);
        }
    }
    const int b    = i0 / RB;                    // 16 | RB, never straddles b
    const int rloc = (i0 % RB) + r4 * 4;
    float4 o;
    o.x = fexp2(acc[0] * 2.885390082f);          // e^{2x} = 2^{2x*log2e}
    o.y = fexp2(acc[1] * 2.885390082f);
    o.z = fexp2(acc[2] * 2.885390082f);
    o.w = fexp2(acc[3] * 2.885390082f);
    *(float4*)(outT + (size_t)b * Hh * RB + (size_t)h * RB + rloc) = o;
}

// ---------------------------------------------------------------------------
// K2: scores -> S[b][q][k]. 1024 blocks (qt<<5 | kt<<3 | b), 256 threads.
// Block = 8 q x 256 k; thread = 8 q x 1 k. eq tile + w2 staged in LDS.
// Masked k-tiles exit immediately. b fastest-varying for load balance.
// ---------------------------------------------------------------------------
__global__ __launch_bounds__(256)
void score_kernel(const float* __restrict__ EqT,
                  const float* __restrict__ EkT,
                  const float* __restrict__ wv,
                  const int* __restrict__ valid_lens,
                  float* __restrict__ S)
{
    __shared__ float eqs[128 * 8];   // 4 KB  [h][8q]
    __shared__ float w2s[128];
    const int blk = blockIdx.x;
    const int b   = blk & 7;
    const int rem = blk >> 3;
    const int kt  = rem & 3;
    const int qt  = rem >> 2;                   // 0..31
    const int len = valid_lens[b];
    if (kt * 256 >= len) return;                // uniform early-exit

    const int tid = threadIdx.x;
    const int k   = kt * 256 + tid;
    const int q0  = qt * 8;

    {   // stage eq tile: 128 h x 8 q, and -2*wv
        const int hh = tid >> 1, part = tid & 1;
        *(float4*)(eqs + hh * 8 + part * 4) =
            *(const float4*)(EqT + (size_t)b * Hh * Qn + (size_t)hh * Qn + q0 + part * 4);
        if (tid < 128) w2s[tid] = -2.0f * wv[tid];
    }
    __syncthreads();

    const float* ekp = EkT + (size_t)b * Hh * Kk + k;
    float a[8];
#pragma unroll
    for (int j = 0; j < 8; ++j) a[j] = 0.f;

#pragma unroll 4
    for (int h = 0; h < Hh; ++h) {
        const float ek = ekp[(size_t)h * Kk];            // coalesced global
        const float w2 = w2s[h];                          // LDS broadcast
        const float4 e0 = *(const float4*)(eqs + h * 8);      // LDS broadcast b128
        const float4 e1 = *(const float4*)(eqs + h * 8 + 4);
        a[0] = fmaf(w2, frcp(fmaf(e0.x, ek, 1.0f)), a[0]);
        a[1] = fmaf(w2, frcp(fmaf(e0.y, ek, 1.0f)), a[1]);
        a[2] = fmaf(w2, frcp(fmaf(e0.z, ek, 1.0f)), a[2]);
        a[3] = fmaf(w2, frcp(fmaf(e0.w, ek, 1.0f)), a[3]);
        a[4] = fmaf(w2, frcp(fmaf(e1.x, ek, 1.0f)), a[4]);
        a[5] = fmaf(w2, frcp(fmaf(e1.y, ek, 1.0f)), a[5]);
        a[6] = fmaf(w2, frcp(fmaf(e1.z, ek, 1.0f)), a[6]);
        a[7] = fmaf(w2, frcp(fmaf(e1.w, ek, 1.0f)), a[7]);
    }
    float* srow = S + (size_t)(b * Qn + q0) * Kk + k;
#pragma unroll
    for (int j = 0; j < 8; ++j) srow[(size_t)j * Kk] = a[j];   // coalesced
}

// ---------------------------------------------------------------------------
// K3: per (b, 4 q): load scores, masked softmax, P@V.
// 512 blocks (qt<<3 | b) x 512 threads; PV uses 16 k-slices x 32 v-lanes.
// ---------------------------------------------------------------------------
__global__ __launch_bounds__(512)
void softmax_pv_kernel(const float* __restrict__ S,
                       const float* __restrict__ values,
                       const int* __restrict__ valid_lens,
                       float* __restrict__ out)
{
    __shared__ float  s_sc[4][Kk];       // 16 KB
    __shared__ float4 s_part[7][4][32];  // 14 KB
    __shared__ float  s_inv[4];

    const int blk  = blockIdx.x;
    const int b    = blk & 7;
    const int q0   = (blk >> 3) << 2;
    const int tid  = threadIdx.x;
    const int lane = tid & 63;
    const int wave = __builtin_amdgcn_readfirstlane(tid >> 6);
    const int len  = valid_lens[b];

    // ---- load scores (k < len only)
#pragma unroll
    for (int j = 0; j < 4; ++j) {
        const float* sr = S + (size_t)(b * Qn + q0 + j) * Kk;
        for (int k = tid; k < len; k += 512) s_sc[j][k] = sr[k];
    }
    __syncthreads();

    // ---- masked softmax, wave w (<4) owns q = w
    if (wave < 4) {
        const int q = wave;
        float m = -3.0e38f;
        for (int i = lane; i < len; i += 64) m = fmaxf(m, s_sc[q][i]);
#pragma unroll
        for (int off = 32; off > 0; off >>= 1) m = fmaxf(m, __shfl_xor(m, off));
        float sum = 0.f;
        for (int i = lane; i < len; i += 64) {
            const float p = fexp2((s_sc[q][i] - m) * 1.44269504f);
            s_sc[q][i] = p;
            sum += p;
        }
#pragma unroll
        for (int off = 32; off > 0; off >>= 1) sum += __shfl_xor(sum, off);
        if (lane == 0) s_inv[q] = frcp(sum);
    }
    __syncthreads();

    // ---- P@V: 16 k-slices x (32 lanes x float4 = 128 v)
    {
        const int slice = tid >> 5;
        const int l32   = tid & 31;
        const int v4    = l32 << 2;
        const float* vp = values + (size_t)b * Kk * DVv + v4;
        float a[4][4];
#pragma unroll
        for (int q = 0; q < 4; ++q) { a[q][0]=0.f; a[q][1]=0.f; a[q][2]=0.f; a[q][3]=0.f; }
        for (int k = slice; k < len; k += 16) {
            const float4 val = *(const float4*)(vp + (size_t)k * DVv);
            const float w0 = s_sc[0][k], w1 = s_sc[1][k], w2 = s_sc[2][k], w3 = s_sc[3][k];
            a[0][0] = fmaf(w0, val.x, a[0][0]);
            a[0][1] = fmaf(w0, val.y, a[0][1]);
            a[0][2] = fmaf(w0, val.z, a[0][2]);
            a[0][3] = fmaf(w0, val.w, a[0][3]);
            a[1][0] = fmaf(w1, val.x, a[1][0]);
            a[1][1] = fmaf(w1, val.y, a[1][1]);
            a[1][2] = fmaf(w1, val.z, a[1][2]);
            a[1][3] = fmaf(w1, val.w, a[1][3]);
            a[2][0] = fmaf(w2, val.x, a[2][0]);
            a[2][1] = fmaf(w2, val.y, a[2][1]);
            a[2][2] = fmaf(w2, val.z, a[2][2]);
            a[2][3] = fmaf(w2, val.w, a[2][3]);
            a[3][0] = fmaf(w3, val.x, a[3][0]);
            a[3][1] = fmaf(w3, val.y, a[3][1]);
            a[3][2] = fmaf(w3, val.z, a[3][2]);
            a[3][3] = fmaf(w3, val.w, a[3][3]);
        }
        // fold the two slices within each wave
#pragma unroll
        for (int q = 0; q < 4; ++q)
#pragma unroll
            for (int x = 0; x < 4; ++x) a[q][x] += __shfl_xor(a[q][x], 32);
        if (wave > 0 && lane < 32) {
#pragma unroll
            for (int q = 0; q < 4; ++q)
                s_part[wave - 1][q][l32] = make_float4(a[q][0], a[q][1], a[q][2], a[q][3]);
        }
        __syncthreads();
        if (wave == 0 && lane < 32) {
#pragma unroll
            for (int q = 0; q < 4; ++q) {
                float r0 = a[q][0], r1 = a[q][1], r2 = a[q][2], r3 = a[q][3];
#pragma unroll
                for (int w = 0; w < 7; ++w) {
                    const float4 p = s_part[w][q][l32];
                    r0 += p.x; r1 += p.y; r2 += p.z; r3 += p.w;
                }
                const float inv = s_inv[q];
                *(float4*)(out + (size_t)(b * Qn + q0 + q) * DVv + v4) =
                    make_float4(r0 * inv, r1 * inv, r2 * inv, r3 * inv);
            }
        }
    }
}

extern "C" void kernel_launch(void* const* d_in, const int* in_sizes, int n_in,
                              void* d_out, int out_size, void* d_ws, size_t ws_size,
                              hipStream_t stream) {
    (void)in_sizes; (void)n_in; (void)out_size; (void)ws_size;
    const float* queries    = (const float*)d_in[0];
    const float* keys       = (const float*)d_in[1];
    const float* values     = (const float*)d_in[2];
    const int*   valid_lens = (const int*)  d_in[3];
    const float* Wq         = (const float*)d_in[4];
    const float* Wk         = (const float*)d_in[5];
    const float* wvv        = (const float*)d_in[6];
    float* out = (float*)d_out;

    float* Wq4T = (float*)d_ws;                                  // 256*128 floats
    float* Wk4T = Wq4T + (size_t)Dd * Hh;
    float* EqT  = Wk4T + (size_t)Dd * Hh;                        // 8*128*256
    float* EkT  = EqT + (size_t)Bb * Hh * Qn;                    // 8*128*1024
    float* S    = EkT + (size_t)Bb * Hh * Kk;                    // 8*256*1024

    repack_w       <<<  64, 256, 0, stream>>>(Wq, Wk, (float4*)Wq4T, (float4*)Wk4T);
    proj_exp_kernel<<< 640, 512, 0, stream>>>(queries, keys, (const float4*)Wq4T,
                                              (const float4*)Wk4T, EqT, EkT);
    score_kernel   <<<1024, 256, 0, stream>>>(EqT, EkT, wvv, valid_lens, S);
    softmax_pv_kernel<<<512, 512, 0, stream>>>(S, values, valid_lens, out);
}